// Round 4
// baseline (2406.675 us; speedup 1.0000x reference)
//
#include <hip/hip_runtime.h>
#include <hip/hip_bf16.h>

#define B_ 2
#define S_ 2048
#define H_ 768
#define NH_ 12
#define HD_ 64
#define L_ 6
#define I_ 3072
#define M_ 256
#define BS_ 4096           // B*S
#define R_ 49152           // B*S*NH
#define EPS_ 1e-6f
#define DN_ 0.35355339059327373f   // 1/sqrt(sqrt(64))
#define RATIO_ 0.0625f             // 1/sqrt(256)

typedef __attribute__((ext_vector_type(8))) short bf16x8;
typedef __attribute__((ext_vector_type(4))) float f32x4;

__device__ __forceinline__ void gload16(const void* g, void* l) {
    __builtin_amdgcn_global_load_lds(
        (const __attribute__((address_space(1))) void*)g,
        (__attribute__((address_space(3))) void*)l, 16, 0, 0);
}

__device__ __forceinline__ float gelu_f(float x) {
    const float c = 0.7978845608028654f;
    float x3 = x * x * x;
    return 0.5f * x * (1.0f + tanhf(c * (x + 0.044715f * x3)));
}

__device__ __forceinline__ void blockReduceSum2(float& a, float& b) {
    __shared__ float sa[4], sb[4];
    int lane = threadIdx.x & 63, wid = threadIdx.x >> 6;
    #pragma unroll
    for (int off = 32; off; off >>= 1) {
        a += __shfl_down(a, off, 64);
        b += __shfl_down(b, off, 64);
    }
    __syncthreads();
    if (lane == 0) { sa[wid] = a; sb[wid] = b; }
    __syncthreads();
    a = sa[0] + sa[1] + sa[2] + sa[3];
    b = sb[0] + sb[1] + sb[2] + sb[3];
    __syncthreads();
}

__device__ __forceinline__ float blockReduceMax(float v) {
    __shared__ float sm[4];
    int lane = threadIdx.x & 63, wid = threadIdx.x >> 6;
    #pragma unroll
    for (int off = 32; off; off >>= 1) v = fmaxf(v, __shfl_down(v, off, 64));
    __syncthreads();
    if (lane == 0) sm[wid] = v;
    __syncthreads();
    float r = fmaxf(fmaxf(sm[0], sm[1]), fmaxf(sm[2], sm[3]));
    __syncthreads();
    return r;
}

__device__ __forceinline__ float blockReduceSum(float v) {
    __shared__ float sm[4];
    int lane = threadIdx.x & 63, wid = threadIdx.x >> 6;
    #pragma unroll
    for (int off = 32; off; off >>= 1) v += __shfl_down(v, off, 64);
    __syncthreads();
    if (lane == 0) sm[wid] = v;
    __syncthreads();
    float r = sm[0] + sm[1] + sm[2] + sm[3];
    __syncthreads();
    return r;
}

// ---------------- bf16 MFMA GEMM, 128x128 tile, BK=32, 4 waves (m97 structure)
// OUTMODE: 0 = fp32 direct stores, 1 = bf16 LDS-bounce, 2 = QKV split bf16 bounce
// RMAXOUT: write per-block row-max partials to rmaxp[blockIdx.x * R_ + row]
template<int ACT, int OUTMODE, int RMAXOUT>
__global__ __launch_bounds__(256) void gemm_mfma_kernel(
    const __hip_bfloat16* __restrict__ A, const __hip_bfloat16* __restrict__ BT,
    const float* __restrict__ bias, void* __restrict__ Cv,
    int N, int K, int lda, int ldb, int ldc, float alpha,
    float* __restrict__ rmaxp)
{
    __shared__ __align__(16) unsigned short smem[8192];   // 16 KB: As(8K) | Bs(8K), reused as Cs
    __shared__ float rmx[128][2];
    unsigned short (*As)[32] = (unsigned short (*)[32])smem;
    unsigned short (*Bs)[32] = (unsigned short (*)[32])(smem + 4096);
    const int tid = threadIdx.x, lane = tid & 63, wid = tid >> 6;
    const int wr = wid >> 1, wc = wid & 1;
    const size_t r0 = (size_t)blockIdx.y * 128;
    const int n0 = blockIdx.x * 128;

    const int srow = lane >> 2;
    const int selem = (lane & 3) * 8;
    const unsigned short* ga0 = (const unsigned short*)A + (r0 + wid * 32 + srow) * (size_t)lda + selem;
    const unsigned short* gb0 = (const unsigned short*)BT + ((size_t)n0 + wid * 32 + srow) * (size_t)ldb + selem;

    f32x4 acc[4][4];
    #pragma unroll
    for (int i = 0; i < 4; i++)
        #pragma unroll
        for (int j = 0; j < 4; j++)
            acc[i][j] = (f32x4){0.f, 0.f, 0.f, 0.f};

    for (int k0 = 0; k0 < K; k0 += 32) {
        gload16(ga0 + k0, &As[wid * 32][0]);
        gload16(ga0 + k0 + 16 * (size_t)lda, &As[wid * 32 + 16][0]);
        gload16(gb0 + k0, &Bs[wid * 32][0]);
        gload16(gb0 + k0 + 16 * (size_t)ldb, &Bs[wid * 32 + 16][0]);
        __syncthreads();
        bf16x8 af[4], bfv[4];
        #pragma unroll
        for (int i = 0; i < 4; i++)
            af[i] = *(const bf16x8*)&As[wr * 64 + i * 16 + (lane & 15)][(lane >> 4) * 8];
        #pragma unroll
        for (int j = 0; j < 4; j++)
            bfv[j] = *(const bf16x8*)&Bs[wc * 64 + j * 16 + (lane & 15)][(lane >> 4) * 8];
        #pragma unroll
        for (int i = 0; i < 4; i++)
            #pragma unroll
            for (int j = 0; j < 4; j++)
                acc[i][j] = __builtin_amdgcn_mfma_f32_16x16x32_bf16(af[i], bfv[j], acc[i][j], 0, 0, 0);
        __syncthreads();
    }

    const int rr = (lane >> 4) * 4;
    const int cc = lane & 15;

    if (OUTMODE == 0) {
        #pragma unroll
        for (int i = 0; i < 4; i++) {
            #pragma unroll
            for (int j = 0; j < 4; j++) {
                int colw = wc * 64 + j * 16 + cc;
                size_t col = (size_t)n0 + colw;
                float bv_ = bias ? bias[col] : 0.f;
                #pragma unroll
                for (int rg = 0; rg < 4; rg++) {
                    size_t row = r0 + wr * 64 + i * 16 + rr + rg;
                    float v = acc[i][j][rg] * alpha + bv_;
                    if (ACT == 1) v = gelu_f(v);
                    ((float*)Cv)[row * ldc + col] = v;
                }
            }
        }
        if (RMAXOUT) {
            #pragma unroll
            for (int i = 0; i < 4; i++) {
                #pragma unroll
                for (int rg = 0; rg < 4; rg++) {
                    float rm = -3.4e38f;
                    #pragma unroll
                    for (int j = 0; j < 4; j++) rm = fmaxf(rm, acc[i][j][rg] * alpha);
                    #pragma unroll
                    for (int off = 1; off <= 8; off <<= 1)
                        rm = fmaxf(rm, __shfl_xor(rm, off, 64));
                    if ((lane & 15) == 0) rmx[wr * 64 + i * 16 + rr + rg][wc] = rm;
                }
            }
            __syncthreads();
            if (tid < 128)
                rmaxp[(size_t)blockIdx.x * R_ + r0 + tid] = fmaxf(rmx[tid][0], rmx[tid][1]);
        }
    } else {
        // bf16 LDS-bounce epilogue: 2 passes of 64 rows through smem (as [64][128] ushort)
        const size_t seg = (size_t)n0 / 768;
        const int colbase = n0 - (int)seg * 768;
        #pragma unroll
        for (int p = 0; p < 2; ++p) {
            if (wr == p) {
                #pragma unroll
                for (int i = 0; i < 4; i++)
                    #pragma unroll
                    for (int j = 0; j < 4; j++) {
                        int colw = wc * 64 + j * 16 + cc;
                        float bv_ = bias ? bias[(size_t)n0 + colw] : 0.f;
                        #pragma unroll
                        for (int rg = 0; rg < 4; rg++) {
                            int lrow = i * 16 + rr + rg;
                            float v = acc[i][j][rg] * alpha + bv_;
                            if (ACT == 1) v = gelu_f(v);
                            int chunk = (colw >> 3) ^ (lrow & 7);   // bank de-conflict swizzle
                            __hip_bfloat16 hb = __float2bfloat16(v);
                            smem[lrow * 128 + chunk * 8 + (colw & 7)] = *(unsigned short*)&hb;
                        }
                    }
            }
            __syncthreads();
            #pragma unroll
            for (int k = 0; k < 4; ++k) {
                int e = tid * 8 + k * 2048;
                int lrow = e >> 7;
                int cst = (e >> 3) & 15;
                int gcol = ((cst ^ (lrow & 7)) << 3);
                bf16x8 val = *(const bf16x8*)&smem[e];
                size_t grow = r0 + p * 64 + lrow;
                unsigned short* dst;
                if (OUTMODE == 1)
                    dst = (unsigned short*)Cv + grow * (size_t)ldc + n0 + gcol;
                else
                    dst = (unsigned short*)Cv + seg * ((size_t)BS_ * H_) + grow * 768 + colbase + gcol;
                *(bf16x8*)dst = val;
            }
            __syncthreads();
        }
    }
}

// ---------------- bf16 MFMA GEMM, 128x64 tile, 4 row-waves, fp32 out
__global__ __launch_bounds__(256) void gemm_mfma_n64_kernel(
    const __hip_bfloat16* __restrict__ A, const __hip_bfloat16* __restrict__ BT,
    const float* __restrict__ bias, float* __restrict__ C,
    int K, int lda, int ldb, int ldc)
{
    __shared__ __align__(16) unsigned short As[128][32];
    __shared__ __align__(16) unsigned short Bs[64][32];
    const int tid = threadIdx.x, lane = tid & 63, wid = tid >> 6;
    const size_t r0 = (size_t)blockIdx.y * 128;
    const int n0 = blockIdx.x * 64;

    const int srow = lane >> 2, selem = (lane & 3) * 8;
    const unsigned short* ga0 = (const unsigned short*)A + (r0 + wid * 32 + srow) * (size_t)lda + selem;
    const unsigned short* gb0 = (const unsigned short*)BT + ((size_t)n0 + wid * 16 + srow) * (size_t)ldb + selem;

    f32x4 acc[2][4];
    #pragma unroll
    for (int i = 0; i < 2; i++)
        #pragma unroll
        for (int j = 0; j < 4; j++)
            acc[i][j] = (f32x4){0.f, 0.f, 0.f, 0.f};

    for (int k0 = 0; k0 < K; k0 += 32) {
        gload16(ga0 + k0, &As[wid * 32][0]);
        gload16(ga0 + k0 + 16 * (size_t)lda, &As[wid * 32 + 16][0]);
        gload16(gb0 + k0, &Bs[wid * 16][0]);
        __syncthreads();
        bf16x8 af[2], bfv[4];
        #pragma unroll
        for (int i = 0; i < 2; i++)
            af[i] = *(const bf16x8*)&As[wid * 32 + i * 16 + (lane & 15)][(lane >> 4) * 8];
        #pragma unroll
        for (int j = 0; j < 4; j++)
            bfv[j] = *(const bf16x8*)&Bs[j * 16 + (lane & 15)][(lane >> 4) * 8];
        #pragma unroll
        for (int i = 0; i < 2; i++)
            #pragma unroll
            for (int j = 0; j < 4; j++)
                acc[i][j] = __builtin_amdgcn_mfma_f32_16x16x32_bf16(af[i], bfv[j], acc[i][j], 0, 0, 0);
        __syncthreads();
    }

    const int rr = (lane >> 4) * 4, cc = lane & 15;
    #pragma unroll
    for (int i = 0; i < 2; i++) {
        #pragma unroll
        for (int j = 0; j < 4; j++) {
            int col = n0 + j * 16 + cc;
            float bv_ = bias ? bias[col] : 0.f;
            #pragma unroll
            for (int rg = 0; rg < 4; rg++) {
                size_t row = r0 + wid * 32 + i * 16 + rr + rg;
                C[row * (size_t)ldc + col] = acc[i][j][rg] + bv_;
            }
        }
    }
}

// ---------------- num = (q' @ kvT^T)/den per head, bf16 MFMA. Grid (16, 24)
__global__ __launch_bounds__(256) void num_mfma_kernel(
    const __hip_bfloat16* __restrict__ QPb, const __hip_bfloat16* __restrict__ kvT,
    const float* __restrict__ den, __hip_bfloat16* __restrict__ ATT)
{
    __shared__ __align__(16) unsigned short As[128][32];
    __shared__ __align__(16) unsigned short Bs[64][32];
    const int tid = threadIdx.x, lane = tid & 63, wid = tid >> 6;
    const int s0 = blockIdx.x * 128;
    const int bn = blockIdx.y, b = bn / NH_, n = bn % NH_;

    const int srow = lane >> 2, selem = (lane & 3) * 8;
    const unsigned short* ga0 = (const unsigned short*)QPb + (size_t)b * S_ * (NH_ * M_) + n * M_
                              + ((size_t)s0 + wid * 32 + srow) * (NH_ * M_) + selem;
    const unsigned short* gb0 = (const unsigned short*)kvT + (size_t)bn * (HD_ * M_)
                              + ((size_t)wid * 16 + srow) * M_ + selem;

    f32x4 acc[2][4];
    #pragma unroll
    for (int i = 0; i < 2; i++)
        #pragma unroll
        for (int j = 0; j < 4; j++)
            acc[i][j] = (f32x4){0.f, 0.f, 0.f, 0.f};

    for (int k0 = 0; k0 < M_; k0 += 32) {
        gload16(ga0 + k0, &As[wid * 32][0]);
        gload16(ga0 + k0 + 16 * (size_t)(NH_ * M_), &As[wid * 32 + 16][0]);
        gload16(gb0 + k0, &Bs[wid * 16][0]);
        __syncthreads();
        bf16x8 af[2], bfv[4];
        #pragma unroll
        for (int i = 0; i < 2; i++)
            af[i] = *(const bf16x8*)&As[wid * 32 + i * 16 + (lane & 15)][(lane >> 4) * 8];
        #pragma unroll
        for (int j = 0; j < 4; j++)
            bfv[j] = *(const bf16x8*)&Bs[j * 16 + (lane & 15)][(lane >> 4) * 8];
        #pragma unroll
        for (int i = 0; i < 2; i++)
            #pragma unroll
            for (int j = 0; j < 4; j++)
                acc[i][j] = __builtin_amdgcn_mfma_f32_16x16x32_bf16(af[i], bfv[j], acc[i][j], 0, 0, 0);
        __syncthreads();
    }

    const int rr = (lane >> 4) * 4, cc = lane & 15;
    #pragma unroll
    for (int i = 0; i < 2; i++) {
        #pragma unroll
        for (int rg = 0; rg < 4; rg++) {
            int s = s0 + wid * 32 + i * 16 + rr + rg;
            float inv = 1.0f / den[((size_t)b * S_ + s) * NH_ + n];
            #pragma unroll
            for (int j = 0; j < 4; j++)
                ATT[((size_t)b * S_ + s) * H_ + n * HD_ + j * 16 + cc]
                    = __float2bfloat16(acc[i][j][rg] * inv);
        }
    }
}

// ---------------- kv split-K: part[(chunk*24+bn)][m][d] = sum over 256 s. Grid (4,24,8)
__global__ __launch_bounds__(256) void kv_splitk_kernel(
    const float* __restrict__ KP, const __hip_bfloat16* __restrict__ Vb, float* __restrict__ part)
{
    const int m0 = blockIdx.x * 64, bn = blockIdx.y, b = bn / NH_, n = bn % NH_;
    const int s0 = blockIdx.z * 256;
    __shared__ __align__(16) float As2[16][68];
    __shared__ __align__(16) float Bs2[16][68];
    const int tid = threadIdx.x, tx = tid & 15, ty = tid >> 4;
    float acc[4][4] = {};
    for (int ss = 0; ss < 256; ss += 16) {
        #pragma unroll
        for (int i = 0; i < 4; i++) {
            int idx = tid + i * 256;
            int kk = idx >> 6, c = idx & 63;
            size_t srow = (size_t)b * S_ + s0 + ss + kk;
            As2[kk][c] = KP[srow * (NH_ * M_) + n * M_ + m0 + c];
            Bs2[kk][c] = __bfloat162float(Vb[srow * H_ + n * HD_ + c]);
        }
        __syncthreads();
        #pragma unroll
        for (int kk = 0; kk < 16; kk++) {
            float4 av = *reinterpret_cast<const float4*>(&As2[kk][ty * 4]);
            float4 bv = *reinterpret_cast<const float4*>(&Bs2[kk][tx * 4]);
            float a4[4] = {av.x, av.y, av.z, av.w};
            float b4[4] = {bv.x, bv.y, bv.z, bv.w};
            #pragma unroll
            for (int i = 0; i < 4; i++)
                #pragma unroll
                for (int j = 0; j < 4; j++)
                    acc[i][j] += a4[i] * b4[j];
        }
        __syncthreads();
    }
    float* Cb = part + ((size_t)blockIdx.z * (B_ * NH_) + bn) * (M_ * HD_);
    #pragma unroll
    for (int i = 0; i < 4; i++)
        #pragma unroll
        for (int j = 0; j < 4; j++)
            Cb[(size_t)(m0 + ty * 4 + i) * HD_ + tx * 4 + j] = acc[i][j];
}

// reduce 8 chunks -> kvT bf16 [bn][d][m]. Grid (24)
__global__ __launch_bounds__(256) void kvred_kernel(
    const float* __restrict__ part, __hip_bfloat16* __restrict__ kvT)
{
    const int bn = blockIdx.x, m = threadIdx.x;
    for (int d = 0; d < HD_; d++) {
        float s = 0.f;
        #pragma unroll
        for (int c = 0; c < 8; c++)
            s += part[((size_t)c * (B_ * NH_) + bn) * (M_ * HD_) + (size_t)m * HD_ + d];
        kvT[(size_t)bn * (HD_ * M_) + (size_t)d * M_ + m] = __float2bfloat16(s);
    }
}

// ---------------- fused per-layer weight prep: 6 transposes + proj convert + bias pack
__global__ __launch_bounds__(256) void prep_kernel(
    const float* __restrict__ wq_l, const float* __restrict__ wk_l,
    const float* __restrict__ wv_l, const float* __restrict__ wo_l,
    const float* __restrict__ wi_l, const float* __restrict__ wo2_l,
    const float* __restrict__ proj_l,
    const float* __restrict__ bq_l, const float* __restrict__ bk_l, const float* __restrict__ bv_l,
    __hip_bfloat16* __restrict__ wqT, __hip_bfloat16* __restrict__ wkT,
    __hip_bfloat16* __restrict__ wvT, __hip_bfloat16* __restrict__ woT,
    __hip_bfloat16* __restrict__ wiT, __hip_bfloat16* __restrict__ wo2T,
    __hip_bfloat16* __restrict__ projb, float* __restrict__ biasq)
{
    __shared__ float tile[32][33];
    int bid = blockIdx.x;
    if (bid < 6912) {
        const float* src; __hip_bfloat16* dst; int K, N, kt, nt;
        if (bid < 2304) {
            int t = bid / 576, idx = bid % 576;
            src = (t == 0) ? wq_l : (t == 1) ? wk_l : (t == 2) ? wv_l : wo_l;
            dst = (t == 0) ? wqT : (t == 1) ? wkT : (t == 2) ? wvT : woT;
            K = 768; N = 768; kt = idx % 24; nt = idx / 24;
        } else if (bid < 4608) {
            int idx = bid - 2304;
            src = wi_l; dst = wiT; K = 768; N = 3072;
            kt = idx % 24; nt = idx / 24;
        } else {
            int idx = bid - 4608;
            src = wo2_l; dst = wo2T; K = 3072; N = 768;
            kt = idx % 96; nt = idx / 96;
        }
        int k0 = kt * 32, n0 = nt * 32;
        int tx = threadIdx.x & 31, ty = threadIdx.x >> 5;
        #pragma unroll
        for (int i = 0; i < 4; i++)
            tile[ty + i * 8][tx] = src[(size_t)(k0 + ty + i * 8) * N + n0 + tx];
        __syncthreads();
        #pragma unroll
        for (int i = 0; i < 4; i++)
            dst[(size_t)(n0 + ty + i * 8) * K + k0 + tx] = __float2bfloat16(tile[tx][ty + i * 8]);
    } else if (bid < 6976) {
        int i = (bid - 6912) * 256 + threadIdx.x;
        projb[i] = __float2bfloat16(proj_l[i]);
    } else {
        int i = (bid - 6976) * 256 + threadIdx.x;
        if (i < 768) biasq[i] = bq_l[i];
        else if (i < 1536) biasq[i] = bk_l[i - 768];
        else if (i < 2304) biasq[i] = bv_l[i - 1536];
    }
}

// x = LN(word_emb + pos_emb + type_emb); fp32 + bf16 shadow
__global__ __launch_bounds__(256) void embed_ln_kernel(
    const int* __restrict__ ids, const int* __restrict__ tts, const int* __restrict__ pos,
    const float* __restrict__ wemb, const float* __restrict__ pemb, const float* __restrict__ temb,
    const float* __restrict__ g, const float* __restrict__ bb,
    float* __restrict__ out, __hip_bfloat16* __restrict__ outb)
{
    size_t row = blockIdx.x;
    int id = ids[row], tt = tts[row], ps = pos[row];
    const float* w0 = wemb + (size_t)id * H_;
    const float* p0 = pemb + (size_t)ps * H_;
    const float* t0 = temb + (size_t)tt * H_;
    float vals[3], s1 = 0.f, s2 = 0.f;
    #pragma unroll
    for (int i = 0; i < 3; i++) {
        int h = threadIdx.x + i * 256;
        float v = w0[h] + p0[h] + t0[h];
        vals[i] = v; s1 += v; s2 += v * v;
    }
    blockReduceSum2(s1, s2);
    float mu = s1 * (1.0f / H_);
    float var = s2 * (1.0f / H_) - mu * mu;
    float rs = rsqrtf(var + EPS_);
    #pragma unroll
    for (int i = 0; i < 3; i++) {
        int h = threadIdx.x + i * 256;
        float y = (vals[i] - mu) * rs * g[h] + bb[h];
        out[row * H_ + h] = y;
        outb[row * H_ + h] = __float2bfloat16(y);
    }
}

// out = LN(P + Q); fp32 + optional bf16 shadow
__global__ __launch_bounds__(256) void add_ln_kernel(
    const float* __restrict__ P, const float* __restrict__ Q,
    const float* __restrict__ g, const float* __restrict__ bb,
    float* __restrict__ out, __hip_bfloat16* __restrict__ outb)
{
    size_t row = blockIdx.x;
    float vals[3], s1 = 0.f, s2 = 0.f;
    #pragma unroll
    for (int i = 0; i < 3; i++) {
        int h = threadIdx.x + i * 256;
        float v = P[row * H_ + h] + Q[row * H_ + h];
        vals[i] = v; s1 += v; s2 += v * v;
    }
    blockReduceSum2(s1, s2);
    float mu = s1 * (1.0f / H_);
    float var = s2 * (1.0f / H_) - mu * mu;
    float rs = rsqrtf(var + EPS_);
    #pragma unroll
    for (int i = 0; i < 3; i++) {
        int h = threadIdx.x + i * 256;
        float y = (vals[i] - mu) * rs * g[h] + bb[h];
        out[row * H_ + h] = y;
        if (outb) outb[row * H_ + h] = __float2bfloat16(y);
    }
}

// rowsq over BOTH Qb and Kb (contiguous): out -> QD then KD (contiguous). Grid 2*R_/4.
__global__ __launch_bounds__(256) void rowsq_bf16_kernel(
    const __hip_bfloat16* __restrict__ X, float* __restrict__ out, float scale)
{
    int lane = threadIdx.x & 63, wid = threadIdx.x >> 6;
    size_t r = (size_t)blockIdx.x * 4 + wid;
    float v = __bfloat162float(X[r * 64 + lane]);
    float s = v * v;
    #pragma unroll
    for (int off = 32; off; off >>= 1) s += __shfl_down(s, off, 64);
    if (lane == 0) out[r] = scale * s;
}

// global (s,m)-max per (b,n) from row-max partials rmaxp[2][R_]. Grid (24)
__global__ __launch_bounds__(256) void gmax_kernel(
    const float* __restrict__ rmaxp, float* __restrict__ gmax)
{
    int bn = blockIdx.x, b = bn / NH_, n = bn % NH_;
    float mx = -3.4e38f;
    for (int s = threadIdx.x; s < S_; s += 256) {
        size_t r = ((size_t)b * S_ + s) * NH_ + n;
        mx = fmaxf(mx, fmaxf(rmaxp[r], rmaxp[R_ + r]));
    }
    mx = blockReduceMax(mx);
    if (threadIdx.x == 0) gmax[bn] = mx;
}

// k' = ratio*(exp(kp-kd-gmax)+eps)*mask in-place; partial ksum per 64-s chunk. Grid (24,32)
__global__ __launch_bounds__(256) void kprime_ksum_kernel(
    float* __restrict__ KP, const float* __restrict__ kd,
    const float* __restrict__ gmax, const int* __restrict__ amask,
    float* __restrict__ kpart)
{
    const int bn = blockIdx.x, chunk = blockIdx.y;
    const int b = bn / NH_, n = bn % NH_;
    const int m = threadIdx.x;
    const float gm = gmax[bn];
    float acc = 0.f;
    for (int si = 0; si < 64; si++) {
        size_t bs = (size_t)b * S_ + chunk * 64 + si;
        size_t r = bs * NH_ + n;
        float mk = (float)amask[bs];
        size_t e = r * M_ + m;
        float v = RATIO_ * (expf(KP[e] - kd[r] - gm) + EPS_) * mk;
        KP[e] = v;
        acc += v;
    }
    kpart[((size_t)bn * 32 + chunk) * M_ + m] = acc;
}

__global__ __launch_bounds__(256) void ksum_final_kernel(
    const float* __restrict__ part, float* __restrict__ ksum)
{
    int bn = blockIdx.x, m = threadIdx.x;
    float s = 0.f;
    #pragma unroll
    for (int c = 0; c < 32; c++) s += part[((size_t)bn * 32 + c) * M_ + m];
    ksum[(size_t)bn * M_ + m] = s;
}

// q' = ratio*(exp(qp-qd-rowmax)+eps) -> bf16; den = sum_m q'*ksum. rowmax from rmaxp partials.
__global__ __launch_bounds__(256) void qprime_den_kernel(
    const float* __restrict__ QP, const float* __restrict__ qd,
    const float* __restrict__ ksum, const float* __restrict__ rmaxp,
    float* __restrict__ den, __hip_bfloat16* __restrict__ QPb)
{
    size_t r = blockIdx.x;
    int n = (int)(r % NH_);
    int b = (int)(r / ((size_t)S_ * NH_));
    int bn = b * NH_ + n;
    float mx = fmaxf(rmaxp[r], rmaxp[R_ + r]);
    float v = QP[r * M_ + threadIdx.x];
    float qp = RATIO_ * (expf(v - qd[r] - mx) + EPS_);
    __hip_bfloat16 qb = __float2bfloat16(qp);
    QPb[r * M_ + threadIdx.x] = qb;
    float qpr = __bfloat162float(qb);
    float d = blockReduceSum(qpr * ksum[(size_t)bn * M_ + threadIdx.x]);
    if (threadIdx.x == 0) den[r] = d;
}

extern "C" void kernel_launch(void* const* d_in, const int* in_sizes, int n_in,
                              void* d_out, int out_size, void* d_ws, size_t ws_size,
                              hipStream_t stream)
{
    const int* input_ids  = (const int*)d_in[0];
    const int* token_type = (const int*)d_in[1];
    const int* position   = (const int*)d_in[2];
    const int* amask      = (const int*)d_in[3];
    const float* wemb = (const float*)d_in[4];
    const float* pemb = (const float*)d_in[5];
    const float* temb = (const float*)d_in[6];
    const float* elng = (const float*)d_in[7];
    const float* elnb = (const float*)d_in[8];
    const float* wq  = (const float*)d_in[9];
    const float* bq  = (const float*)d_in[10];
    const float* wk  = (const float*)d_in[11];
    const float* bk  = (const float*)d_in[12];
    const float* wv  = (const float*)d_in[13];
    const float* bv  = (const float*)d_in[14];
    const float* wo  = (const float*)d_in[15];
    const float* bo  = (const float*)d_in[16];
    const float* ln1g = (const float*)d_in[17];
    const float* ln1b = (const float*)d_in[18];
    const float* wi  = (const float*)d_in[19];
    const float* bi  = (const float*)d_in[20];
    const float* wo2 = (const float*)d_in[21];
    const float* bo2 = (const float*)d_in[22];
    const float* ln2g = (const float*)d_in[23];
    const float* ln2b = (const float*)d_in[24];
    const float* proj = (const float*)d_in[25];

    float* ws = (float*)d_ws;
    float* X    = ws;                          // 3145728
    float* T2   = X + 3145728;                 // 3145728
    float* BIG  = T2 + 3145728;                // 12582912
    float* U    = BIG + 12582912;              // 6291456 (PART fp32 3.1M f / QPb bf16 12.58M el)
    __hip_bfloat16* Xb  = (__hip_bfloat16*)(U + 6291456);            // 3145728 el
    __hip_bfloat16* Qb  = (__hip_bfloat16*)((float*)Xb + 1572864);   // Qb|Kb|Vb contiguous
    __hip_bfloat16* Kb  = Qb + 3145728;
    __hip_bfloat16* Vb  = Kb + 3145728;
    __hip_bfloat16* BF1 = Vb + 3145728;                              // 3145728 el
    __hip_bfloat16* WT  = BF1 + 3145728;                             // 7094272 el
    float* kvT_f = (float*)(WT + 7094272);     // kvT bf16 393216 el = 196608 f
    __hip_bfloat16* kvT = (__hip_bfloat16*)kvT_f;
    float* KSUM  = kvT_f + 196608;             // 6144
    float* KPART = KSUM + 6144;                // 196608 (24*32*256)
    float* RMAXP = KPART + 196608;             // 98304 ([2][R_])
    float* GMAX  = RMAXP + 98304;              // 64
    float* QD    = GMAX + 64;                  // 49152  (KD must follow)
    float* KD    = QD + 49152;                 // 49152
    float* DEN   = KD + 49152;                 // 49152
    float* BIASQ = DEN + 49152;                // 2304
    float* T1    = (float*)d_out;              // [4096,768] scratch aliasing output

    __hip_bfloat16* wqT  = WT;                 // packed QKV^T contiguous [2304,768]
    __hip_bfloat16* wkT  = wqT + 589824;
    __hip_bfloat16* wvT  = wkT + 589824;
    __hip_bfloat16* woT  = wvT + 589824;
    __hip_bfloat16* wiT  = woT + 589824;
    __hip_bfloat16* wo2T = wiT + 2359296;
    __hip_bfloat16* projb = wo2T + 2359296;    // 16384 el
    __hip_bfloat16* QPb = (__hip_bfloat16*)U;
    float* PART = U;
    __hip_bfloat16* BIGb = (__hip_bfloat16*)BIG;

    embed_ln_kernel<<<BS_, 256, 0, stream>>>(input_ids, token_type, position,
        wemb, pemb, temb, elng, elnb, X, Xb);

    const float sqscale = 0.5f * DN_ * DN_;
    for (int l = 0; l < L_; l++) {
        const float* wq_l = wq + (size_t)l * H_ * NH_ * HD_;
        const float* wk_l = wk + (size_t)l * H_ * NH_ * HD_;
        const float* wv_l = wv + (size_t)l * H_ * NH_ * HD_;
        const float* wo_l = wo + (size_t)l * NH_ * HD_ * H_;
        const float* bq_l = bq + (size_t)l * NH_ * HD_;
        const float* bk_l = bk + (size_t)l * NH_ * HD_;
        const float* bv_l = bv + (size_t)l * NH_ * HD_;
        const float* bo_l = bo + (size_t)l * H_;
        const float* wi_l = wi + (size_t)l * H_ * I_;
        const float* bi_l = bi + (size_t)l * I_;
        const float* wo2_l = wo2 + (size_t)l * I_ * H_;
        const float* bo2_l = bo2 + (size_t)l * H_;
        const float* proj_l = proj + (size_t)l * M_ * HD_;

        // ---- fused weight prep (1 launch) ----
        prep_kernel<<<6985, 256, 0, stream>>>(wq_l, wk_l, wv_l, wo_l, wi_l, wo2_l, proj_l,
            bq_l, bk_l, bv_l, wqT, wkT, wvT, woT, wiT, wo2T, projb, BIASQ);

        // ---- fused QKV GEMM -> Qb|Kb|Vb bf16 ----
        gemm_mfma_kernel<0,2,0><<<dim3(18,32), 256, 0, stream>>>(
            Xb, wqT, BIASQ, (void*)Qb, 2304, 768, 768, 768, 768, 1.f, nullptr);

        // ---- qd & kd in one pass (Qb,Kb contiguous; QD,KD contiguous) ----
        rowsq_bf16_kernel<<<2*R_/4, 256, 0, stream>>>(Qb, QD, sqscale);

        // ---- K path ----
        gemm_mfma_kernel<0,0,1><<<dim3(2,384), 256, 0, stream>>>(
            Kb, projb, nullptr, BIG, 256, 64, 64, 64, 256, DN_, RMAXP);
        gmax_kernel<<<B_*NH_, 256, 0, stream>>>(RMAXP, GMAX);
        kprime_ksum_kernel<<<dim3(B_*NH_, 32), 256, 0, stream>>>(BIG, KD, GMAX, amask, KPART);
        ksum_final_kernel<<<B_*NH_, 256, 0, stream>>>(KPART, KSUM);
        kv_splitk_kernel<<<dim3(4, B_*NH_, 8), 256, 0, stream>>>(BIG, Vb, PART);
        kvred_kernel<<<B_*NH_, 256, 0, stream>>>(PART, kvT);

        // ---- Q path ----
        gemm_mfma_kernel<0,0,1><<<dim3(2,384), 256, 0, stream>>>(
            Qb, projb, nullptr, BIG, 256, 64, 64, 64, 256, DN_, RMAXP);
        qprime_den_kernel<<<R_, 256, 0, stream>>>(BIG, QD, KSUM, RMAXP, DEN, QPb);
        num_mfma_kernel<<<dim3(16, B_*NH_), 256, 0, stream>>>(QPb, kvT, DEN, BF1);

        // ---- attn out proj + LN1 ----
        gemm_mfma_n64_kernel<<<dim3(12,32), 256, 0, stream>>>(
            BF1, woT, bo_l, T1, 768, 768, 768, 768);
        add_ln_kernel<<<BS_, 256, 0, stream>>>(T1, X, ln1g + (size_t)l*H_, ln1b + (size_t)l*H_, T2, BF1);

        // ---- FFN + LN2 ----
        gemm_mfma_kernel<1,1,0><<<dim3(24,32), 256, 0, stream>>>(
            BF1, wiT, bi_l, (void*)BIGb, 3072, 768, 768, 768, 3072, 1.f, nullptr);
        gemm_mfma_n64_kernel<<<dim3(12,32), 256, 0, stream>>>(
            BIGb, wo2T, bo2_l, T1, 3072, 3072, 3072, 768);
        float* xout = (l == L_ - 1) ? (float*)d_out : X;
        add_ln_kernel<<<BS_, 256, 0, stream>>>(T1, T2, ln2g + (size_t)l*H_, ln2b + (size_t)l*H_, xout, Xb);
    }
}

// Round 5
// 1918.404 us; speedup vs baseline: 1.2545x; 1.2545x over previous
//
#include <hip/hip_runtime.h>
#include <hip/hip_bf16.h>

#define B_ 2
#define S_ 2048
#define H_ 768
#define NH_ 12
#define HD_ 64
#define L_ 6
#define I_ 3072
#define M_ 256
#define BS_ 4096           // B*S
#define R_ 49152           // B*S*NH
#define EPS_ 1e-6f
#define DN_ 0.35355339059327373f   // 1/sqrt(sqrt(64))
#define RATIO_ 0.0625f             // 1/sqrt(256)

typedef __attribute__((ext_vector_type(8))) short bf16x8;
typedef __attribute__((ext_vector_type(4))) float f32x4;

__device__ __forceinline__ void gload16(const void* g, void* l) {
    __builtin_amdgcn_global_load_lds(
        (const __attribute__((address_space(1))) void*)g,
        (__attribute__((address_space(3))) void*)l, 16, 0, 0);
}

__device__ __forceinline__ float gelu_f(float x) {
    const float c = 0.7978845608028654f;
    float x3 = x * x * x;
    return 0.5f * x * (1.0f + tanhf(c * (x + 0.044715f * x3)));
}

__device__ __forceinline__ void blockReduceSum2(float& a, float& b) {
    __shared__ float sa[4], sb[4];
    int lane = threadIdx.x & 63, wid = threadIdx.x >> 6;
    #pragma unroll
    for (int off = 32; off; off >>= 1) {
        a += __shfl_down(a, off, 64);
        b += __shfl_down(b, off, 64);
    }
    __syncthreads();
    if (lane == 0) { sa[wid] = a; sb[wid] = b; }
    __syncthreads();
    a = sa[0] + sa[1] + sa[2] + sa[3];
    b = sb[0] + sb[1] + sb[2] + sb[3];
    __syncthreads();
}

__device__ __forceinline__ float blockReduceMax(float v) {
    __shared__ float sm[4];
    int lane = threadIdx.x & 63, wid = threadIdx.x >> 6;
    #pragma unroll
    for (int off = 32; off; off >>= 1) v = fmaxf(v, __shfl_down(v, off, 64));
    __syncthreads();
    if (lane == 0) sm[wid] = v;
    __syncthreads();
    float r = fmaxf(fmaxf(sm[0], sm[1]), fmaxf(sm[2], sm[3]));
    __syncthreads();
    return r;
}

__device__ __forceinline__ float blockReduceSum(float v) {
    __shared__ float sm[4];
    int lane = threadIdx.x & 63, wid = threadIdx.x >> 6;
    #pragma unroll
    for (int off = 32; off; off >>= 1) v += __shfl_down(v, off, 64);
    __syncthreads();
    if (lane == 0) sm[wid] = v;
    __syncthreads();
    float r = sm[0] + sm[1] + sm[2] + sm[3];
    __syncthreads();
    return r;
}

// ---------------- bf16 MFMA GEMM, 128x128 tile, BK=32, 4 waves, 2-phase dbuf
// OUTMODE: 0 = fp32 direct stores, 1 = bf16 direct stores, 2 = QKV split bf16
// RMAXOUT: write per-block row-max partials to rmaxp[blockIdx.x * R_ + row]
template<int ACT, int OUTMODE, int RMAXOUT>
__global__ __launch_bounds__(256) void gemm_mfma_kernel(
    const __hip_bfloat16* __restrict__ A, const __hip_bfloat16* __restrict__ BT,
    const float* __restrict__ bias, void* __restrict__ Cv,
    int N, int K, int lda, int ldb, int ldc, float alpha,
    float* __restrict__ rmaxp)
{
    __shared__ __align__(16) unsigned short As[2][128][32];
    __shared__ __align__(16) unsigned short Bs[2][128][32];
    __shared__ float rmx[128][2];
    const int tid = threadIdx.x, lane = tid & 63, wid = tid >> 6;
    const int wr = wid >> 1, wc = wid & 1;
    const size_t r0 = (size_t)blockIdx.y * 128;
    const int n0 = blockIdx.x * 128;

    const int srow = lane >> 2;
    const int selem = (lane & 3) * 8;
    const unsigned short* ga0 = (const unsigned short*)A + (r0 + wid * 32 + srow) * (size_t)lda + selem;
    const unsigned short* gb0 = (const unsigned short*)BT + ((size_t)n0 + wid * 32 + srow) * (size_t)ldb + selem;

    f32x4 acc[4][4];
    #pragma unroll
    for (int i = 0; i < 4; i++)
        #pragma unroll
        for (int j = 0; j < 4; j++)
            acc[i][j] = (f32x4){0.f, 0.f, 0.f, 0.f};

    // prologue: stage k0=0 into buffer 0
    gload16(ga0, &As[0][wid * 32][0]);
    gload16(ga0 + 16 * (size_t)lda, &As[0][wid * 32 + 16][0]);
    gload16(gb0, &Bs[0][wid * 32][0]);
    gload16(gb0 + 16 * (size_t)ldb, &Bs[0][wid * 32 + 16][0]);
    __syncthreads();

    int cur = 0;
    for (int k0 = 0; k0 < K; k0 += 32) {
        const int kn = k0 + 32;
        if (kn < K) {   // stage next tile into other buffer (flies under this step's compute)
            gload16(ga0 + kn, &As[cur ^ 1][wid * 32][0]);
            gload16(ga0 + kn + 16 * (size_t)lda, &As[cur ^ 1][wid * 32 + 16][0]);
            gload16(gb0 + kn, &Bs[cur ^ 1][wid * 32][0]);
            gload16(gb0 + kn + 16 * (size_t)ldb, &Bs[cur ^ 1][wid * 32 + 16][0]);
        }
        bf16x8 af[4], bfv[4];
        #pragma unroll
        for (int i = 0; i < 4; i++)
            af[i] = *(const bf16x8*)&As[cur][wr * 64 + i * 16 + (lane & 15)][(lane >> 4) * 8];
        #pragma unroll
        for (int j = 0; j < 4; j++)
            bfv[j] = *(const bf16x8*)&Bs[cur][wc * 64 + j * 16 + (lane & 15)][(lane >> 4) * 8];
        #pragma unroll
        for (int i = 0; i < 4; i++)
            #pragma unroll
            for (int j = 0; j < 4; j++)
                acc[i][j] = __builtin_amdgcn_mfma_f32_16x16x32_bf16(af[i], bfv[j], acc[i][j], 0, 0, 0);
        __syncthreads();   // drains lgkm (reads of cur) + vmcnt (stages of cur^1)
        cur ^= 1;
    }

    const int rr = (lane >> 4) * 4;
    const int cc = lane & 15;
    const size_t seg = (size_t)n0 / 768;          // OUTMODE==2: which of Q/K/V
    const int colbase = n0 - (int)seg * 768;
    #pragma unroll
    for (int i = 0; i < 4; i++) {
        #pragma unroll
        for (int j = 0; j < 4; j++) {
            int colw = wc * 64 + j * 16 + cc;
            size_t col = (size_t)n0 + colw;
            float bv_ = bias ? bias[col] : 0.f;
            #pragma unroll
            for (int rg = 0; rg < 4; rg++) {
                size_t row = r0 + wr * 64 + i * 16 + rr + rg;
                float v = acc[i][j][rg] * alpha + bv_;
                if (ACT == 1) v = gelu_f(v);
                if (OUTMODE == 0)
                    ((float*)Cv)[row * ldc + col] = v;
                else if (OUTMODE == 1)
                    ((__hip_bfloat16*)Cv)[row * ldc + col] = __float2bfloat16(v);
                else
                    ((__hip_bfloat16*)Cv)[seg * ((size_t)BS_ * H_) + row * 768 + colbase + colw]
                        = __float2bfloat16(v);
            }
        }
    }
    if (RMAXOUT) {
        #pragma unroll
        for (int i = 0; i < 4; i++) {
            #pragma unroll
            for (int rg = 0; rg < 4; rg++) {
                float rm = -3.4e38f;
                #pragma unroll
                for (int j = 0; j < 4; j++) rm = fmaxf(rm, acc[i][j][rg] * alpha);
                #pragma unroll
                for (int off = 1; off <= 8; off <<= 1)
                    rm = fmaxf(rm, __shfl_xor(rm, off, 64));
                if ((lane & 15) == 0) rmx[wr * 64 + i * 16 + rr + rg][wc] = rm;
            }
        }
        __syncthreads();
        if (tid < 128)
            rmaxp[(size_t)blockIdx.x * R_ + r0 + tid] = fmaxf(rmx[tid][0], rmx[tid][1]);
    }
}

// ---------------- bf16 MFMA GEMM, 128x64 tile, 4 row-waves, fp32 out, 2-phase dbuf
__global__ __launch_bounds__(256) void gemm_mfma_n64_kernel(
    const __hip_bfloat16* __restrict__ A, const __hip_bfloat16* __restrict__ BT,
    const float* __restrict__ bias, float* __restrict__ C,
    int K, int lda, int ldb, int ldc)
{
    __shared__ __align__(16) unsigned short As[2][128][32];
    __shared__ __align__(16) unsigned short Bs[2][64][32];
    const int tid = threadIdx.x, lane = tid & 63, wid = tid >> 6;
    const size_t r0 = (size_t)blockIdx.y * 128;
    const int n0 = blockIdx.x * 64;

    const int srow = lane >> 2, selem = (lane & 3) * 8;
    const unsigned short* ga0 = (const unsigned short*)A + (r0 + wid * 32 + srow) * (size_t)lda + selem;
    const unsigned short* gb0 = (const unsigned short*)BT + ((size_t)n0 + wid * 16 + srow) * (size_t)ldb + selem;

    f32x4 acc[2][4];
    #pragma unroll
    for (int i = 0; i < 2; i++)
        #pragma unroll
        for (int j = 0; j < 4; j++)
            acc[i][j] = (f32x4){0.f, 0.f, 0.f, 0.f};

    gload16(ga0, &As[0][wid * 32][0]);
    gload16(ga0 + 16 * (size_t)lda, &As[0][wid * 32 + 16][0]);
    gload16(gb0, &Bs[0][wid * 16][0]);
    __syncthreads();

    int cur = 0;
    for (int k0 = 0; k0 < K; k0 += 32) {
        const int kn = k0 + 32;
        if (kn < K) {
            gload16(ga0 + kn, &As[cur ^ 1][wid * 32][0]);
            gload16(ga0 + kn + 16 * (size_t)lda, &As[cur ^ 1][wid * 32 + 16][0]);
            gload16(gb0 + kn, &Bs[cur ^ 1][wid * 16][0]);
        }
        bf16x8 af[2], bfv[4];
        #pragma unroll
        for (int i = 0; i < 2; i++)
            af[i] = *(const bf16x8*)&As[cur][wid * 32 + i * 16 + (lane & 15)][(lane >> 4) * 8];
        #pragma unroll
        for (int j = 0; j < 4; j++)
            bfv[j] = *(const bf16x8*)&Bs[cur][j * 16 + (lane & 15)][(lane >> 4) * 8];
        #pragma unroll
        for (int i = 0; i < 2; i++)
            #pragma unroll
            for (int j = 0; j < 4; j++)
                acc[i][j] = __builtin_amdgcn_mfma_f32_16x16x32_bf16(af[i], bfv[j], acc[i][j], 0, 0, 0);
        __syncthreads();
        cur ^= 1;
    }

    const int rr = (lane >> 4) * 4, cc = lane & 15;
    #pragma unroll
    for (int i = 0; i < 2; i++) {
        #pragma unroll
        for (int j = 0; j < 4; j++) {
            int col = n0 + j * 16 + cc;
            float bv_ = bias ? bias[col] : 0.f;
            #pragma unroll
            for (int rg = 0; rg < 4; rg++) {
                size_t row = r0 + wid * 32 + i * 16 + rr + rg;
                C[row * (size_t)ldc + col] = acc[i][j][rg] + bv_;
            }
        }
    }
}

// ---------------- num = (q' @ kvT^T)/den per head, bf16 MFMA, 2-phase dbuf. Grid (16, 24)
__global__ __launch_bounds__(256) void num_mfma_kernel(
    const __hip_bfloat16* __restrict__ QPb, const __hip_bfloat16* __restrict__ kvT,
    const float* __restrict__ den, __hip_bfloat16* __restrict__ ATT)
{
    __shared__ __align__(16) unsigned short As[2][128][32];
    __shared__ __align__(16) unsigned short Bs[2][64][32];
    const int tid = threadIdx.x, lane = tid & 63, wid = tid >> 6;
    const int s0 = blockIdx.x * 128;
    const int bn = blockIdx.y, b = bn / NH_, n = bn % NH_;

    const int srow = lane >> 2, selem = (lane & 3) * 8;
    const unsigned short* ga0 = (const unsigned short*)QPb + (size_t)b * S_ * (NH_ * M_) + n * M_
                              + ((size_t)s0 + wid * 32 + srow) * (NH_ * M_) + selem;
    const unsigned short* gb0 = (const unsigned short*)kvT + (size_t)bn * (HD_ * M_)
                              + ((size_t)wid * 16 + srow) * M_ + selem;

    f32x4 acc[2][4];
    #pragma unroll
    for (int i = 0; i < 2; i++)
        #pragma unroll
        for (int j = 0; j < 4; j++)
            acc[i][j] = (f32x4){0.f, 0.f, 0.f, 0.f};

    gload16(ga0, &As[0][wid * 32][0]);
    gload16(ga0 + 16 * (size_t)(NH_ * M_), &As[0][wid * 32 + 16][0]);
    gload16(gb0, &Bs[0][wid * 16][0]);
    __syncthreads();

    int cur = 0;
    for (int k0 = 0; k0 < M_; k0 += 32) {
        const int kn = k0 + 32;
        if (kn < M_) {
            gload16(ga0 + kn, &As[cur ^ 1][wid * 32][0]);
            gload16(ga0 + kn + 16 * (size_t)(NH_ * M_), &As[cur ^ 1][wid * 32 + 16][0]);
            gload16(gb0 + kn, &Bs[cur ^ 1][wid * 16][0]);
        }
        bf16x8 af[2], bfv[4];
        #pragma unroll
        for (int i = 0; i < 2; i++)
            af[i] = *(const bf16x8*)&As[cur][wid * 32 + i * 16 + (lane & 15)][(lane >> 4) * 8];
        #pragma unroll
        for (int j = 0; j < 4; j++)
            bfv[j] = *(const bf16x8*)&Bs[cur][j * 16 + (lane & 15)][(lane >> 4) * 8];
        #pragma unroll
        for (int i = 0; i < 2; i++)
            #pragma unroll
            for (int j = 0; j < 4; j++)
                acc[i][j] = __builtin_amdgcn_mfma_f32_16x16x32_bf16(af[i], bfv[j], acc[i][j], 0, 0, 0);
        __syncthreads();
        cur ^= 1;
    }

    const int rr = (lane >> 4) * 4, cc = lane & 15;
    #pragma unroll
    for (int i = 0; i < 2; i++) {
        #pragma unroll
        for (int rg = 0; rg < 4; rg++) {
            int s = s0 + wid * 32 + i * 16 + rr + rg;
            float inv = 1.0f / den[((size_t)b * S_ + s) * NH_ + n];
            #pragma unroll
            for (int j = 0; j < 4; j++)
                ATT[((size_t)b * S_ + s) * H_ + n * HD_ + j * 16 + cc]
                    = __float2bfloat16(acc[i][j][rg] * inv);
        }
    }
}

// ---------------- kv split-K: part[(chunk*24+bn)][m][d] = sum over 256 s. Grid (4,24,8)
__global__ __launch_bounds__(256) void kv_splitk_kernel(
    const float* __restrict__ KP, const __hip_bfloat16* __restrict__ Vb, float* __restrict__ part)
{
    const int m0 = blockIdx.x * 64, bn = blockIdx.y, b = bn / NH_, n = bn % NH_;
    const int s0 = blockIdx.z * 256;
    __shared__ __align__(16) float As2[16][68];
    __shared__ __align__(16) float Bs2[16][68];
    const int tid = threadIdx.x, tx = tid & 15, ty = tid >> 4;
    float acc[4][4] = {};
    for (int ss = 0; ss < 256; ss += 16) {
        #pragma unroll
        for (int i = 0; i < 4; i++) {
            int idx = tid + i * 256;
            int kk = idx >> 6, c = idx & 63;
            size_t srow = (size_t)b * S_ + s0 + ss + kk;
            As2[kk][c] = KP[srow * (NH_ * M_) + n * M_ + m0 + c];
            Bs2[kk][c] = __bfloat162float(Vb[srow * H_ + n * HD_ + c]);
        }
        __syncthreads();
        #pragma unroll
        for (int kk = 0; kk < 16; kk++) {
            float4 av = *reinterpret_cast<const float4*>(&As2[kk][ty * 4]);
            float4 bv = *reinterpret_cast<const float4*>(&Bs2[kk][tx * 4]);
            float a4[4] = {av.x, av.y, av.z, av.w};
            float b4[4] = {bv.x, bv.y, bv.z, bv.w};
            #pragma unroll
            for (int i = 0; i < 4; i++)
                #pragma unroll
                for (int j = 0; j < 4; j++)
                    acc[i][j] += a4[i] * b4[j];
        }
        __syncthreads();
    }
    float* Cb = part + ((size_t)blockIdx.z * (B_ * NH_) + bn) * (M_ * HD_);
    #pragma unroll
    for (int i = 0; i < 4; i++)
        #pragma unroll
        for (int j = 0; j < 4; j++)
            Cb[(size_t)(m0 + ty * 4 + i) * HD_ + tx * 4 + j] = acc[i][j];
}

// reduce 8 chunks -> kvT bf16 [bn][d][m]. Grid (24)
__global__ __launch_bounds__(256) void kvred_kernel(
    const float* __restrict__ part, __hip_bfloat16* __restrict__ kvT)
{
    const int bn = blockIdx.x, m = threadIdx.x;
    for (int d = 0; d < HD_; d++) {
        float s = 0.f;
        #pragma unroll
        for (int c = 0; c < 8; c++)
            s += part[((size_t)c * (B_ * NH_) + bn) * (M_ * HD_) + (size_t)m * HD_ + d];
        kvT[(size_t)bn * (HD_ * M_) + (size_t)d * M_ + m] = __float2bfloat16(s);
    }
}

// ---------------- fused per-layer weight prep: 6 transposes + proj convert + bias pack
__global__ __launch_bounds__(256) void prep_kernel(
    const float* __restrict__ wq_l, const float* __restrict__ wk_l,
    const float* __restrict__ wv_l, const float* __restrict__ wo_l,
    const float* __restrict__ wi_l, const float* __restrict__ wo2_l,
    const float* __restrict__ proj_l,
    const float* __restrict__ bq_l, const float* __restrict__ bk_l, const float* __restrict__ bv_l,
    __hip_bfloat16* __restrict__ wqT, __hip_bfloat16* __restrict__ wkT,
    __hip_bfloat16* __restrict__ wvT, __hip_bfloat16* __restrict__ woT,
    __hip_bfloat16* __restrict__ wiT, __hip_bfloat16* __restrict__ wo2T,
    __hip_bfloat16* __restrict__ projb, float* __restrict__ biasq)
{
    __shared__ float tile[32][33];
    int bid = blockIdx.x;
    if (bid < 6912) {
        const float* src; __hip_bfloat16* dst; int K, N, kt, nt;
        if (bid < 2304) {
            int t = bid / 576, idx = bid % 576;
            src = (t == 0) ? wq_l : (t == 1) ? wk_l : (t == 2) ? wv_l : wo_l;
            dst = (t == 0) ? wqT : (t == 1) ? wkT : (t == 2) ? wvT : woT;
            K = 768; N = 768; kt = idx % 24; nt = idx / 24;
        } else if (bid < 4608) {
            int idx = bid - 2304;
            src = wi_l; dst = wiT; K = 768; N = 3072;
            kt = idx % 24; nt = idx / 24;
        } else {
            int idx = bid - 4608;
            src = wo2_l; dst = wo2T; K = 3072; N = 768;
            kt = idx % 96; nt = idx / 96;
        }
        int k0 = kt * 32, n0 = nt * 32;
        int tx = threadIdx.x & 31, ty = threadIdx.x >> 5;
        #pragma unroll
        for (int i = 0; i < 4; i++)
            tile[ty + i * 8][tx] = src[(size_t)(k0 + ty + i * 8) * N + n0 + tx];
        __syncthreads();
        #pragma unroll
        for (int i = 0; i < 4; i++)
            dst[(size_t)(n0 + ty + i * 8) * K + k0 + tx] = __float2bfloat16(tile[tx][ty + i * 8]);
    } else if (bid < 6976) {
        int i = (bid - 6912) * 256 + threadIdx.x;
        projb[i] = __float2bfloat16(proj_l[i]);
    } else {
        int i = (bid - 6976) * 256 + threadIdx.x;
        if (i < 768) biasq[i] = bq_l[i];
        else if (i < 1536) biasq[i] = bk_l[i - 768];
        else if (i < 2304) biasq[i] = bv_l[i - 1536];
    }
}

// x = LN(word_emb + pos_emb + type_emb); fp32 + bf16 shadow
__global__ __launch_bounds__(256) void embed_ln_kernel(
    const int* __restrict__ ids, const int* __restrict__ tts, const int* __restrict__ pos,
    const float* __restrict__ wemb, const float* __restrict__ pemb, const float* __restrict__ temb,
    const float* __restrict__ g, const float* __restrict__ bb,
    float* __restrict__ out, __hip_bfloat16* __restrict__ outb)
{
    size_t row = blockIdx.x;
    int id = ids[row], tt = tts[row], ps = pos[row];
    const float* w0 = wemb + (size_t)id * H_;
    const float* p0 = pemb + (size_t)ps * H_;
    const float* t0 = temb + (size_t)tt * H_;
    float vals[3], s1 = 0.f, s2 = 0.f;
    #pragma unroll
    for (int i = 0; i < 3; i++) {
        int h = threadIdx.x + i * 256;
        float v = w0[h] + p0[h] + t0[h];
        vals[i] = v; s1 += v; s2 += v * v;
    }
    blockReduceSum2(s1, s2);
    float mu = s1 * (1.0f / H_);
    float var = s2 * (1.0f / H_) - mu * mu;
    float rs = rsqrtf(var + EPS_);
    #pragma unroll
    for (int i = 0; i < 3; i++) {
        int h = threadIdx.x + i * 256;
        float y = (vals[i] - mu) * rs * g[h] + bb[h];
        out[row * H_ + h] = y;
        outb[row * H_ + h] = __float2bfloat16(y);
    }
}

// out = LN(P + Q); fp32 + optional bf16 shadow
__global__ __launch_bounds__(256) void add_ln_kernel(
    const float* __restrict__ P, const float* __restrict__ Q,
    const float* __restrict__ g, const float* __restrict__ bb,
    float* __restrict__ out, __hip_bfloat16* __restrict__ outb)
{
    size_t row = blockIdx.x;
    float vals[3], s1 = 0.f, s2 = 0.f;
    #pragma unroll
    for (int i = 0; i < 3; i++) {
        int h = threadIdx.x + i * 256;
        float v = P[row * H_ + h] + Q[row * H_ + h];
        vals[i] = v; s1 += v; s2 += v * v;
    }
    blockReduceSum2(s1, s2);
    float mu = s1 * (1.0f / H_);
    float var = s2 * (1.0f / H_) - mu * mu;
    float rs = rsqrtf(var + EPS_);
    #pragma unroll
    for (int i = 0; i < 3; i++) {
        int h = threadIdx.x + i * 256;
        float y = (vals[i] - mu) * rs * g[h] + bb[h];
        out[row * H_ + h] = y;
        if (outb) outb[row * H_ + h] = __float2bfloat16(y);
    }
}

// rowsq over rows of width 64 (wave per row)
__global__ __launch_bounds__(256) void rowsq_bf16_kernel(
    const __hip_bfloat16* __restrict__ X, float* __restrict__ out, float scale)
{
    int lane = threadIdx.x & 63, wid = threadIdx.x >> 6;
    size_t r = (size_t)blockIdx.x * 4 + wid;
    float v = __bfloat162float(X[r * 64 + lane]);
    float s = v * v;
    #pragma unroll
    for (int off = 32; off; off >>= 1) s += __shfl_down(s, off, 64);
    if (lane == 0) out[r] = scale * s;
}

// global (s,m)-max per (b,n) from row-max partials rmaxp[2][R_]. Grid (24)
__global__ __launch_bounds__(256) void gmax_kernel(
    const float* __restrict__ rmaxp, float* __restrict__ gmax)
{
    int bn = blockIdx.x, b = bn / NH_, n = bn % NH_;
    float mx = -3.4e38f;
    for (int s = threadIdx.x; s < S_; s += 256) {
        size_t r = ((size_t)b * S_ + s) * NH_ + n;
        mx = fmaxf(mx, fmaxf(rmaxp[r], rmaxp[R_ + r]));
    }
    mx = blockReduceMax(mx);
    if (threadIdx.x == 0) gmax[bn] = mx;
}

// k' = ratio*(exp(kp-kd-gmax)+eps)*mask in-place; partial ksum per 64-s chunk. Grid (24,32)
__global__ __launch_bounds__(256) void kprime_ksum_kernel(
    float* __restrict__ KP, const float* __restrict__ kd,
    const float* __restrict__ gmax, const int* __restrict__ amask,
    float* __restrict__ kpart)
{
    const int bn = blockIdx.x, chunk = blockIdx.y;
    const int b = bn / NH_, n = bn % NH_;
    const int m = threadIdx.x;
    const float gm = gmax[bn];
    float acc = 0.f;
    for (int si = 0; si < 64; si++) {
        size_t bs = (size_t)b * S_ + chunk * 64 + si;
        size_t r = bs * NH_ + n;
        float mk = (float)amask[bs];
        size_t e = r * M_ + m;
        float v = RATIO_ * (expf(KP[e] - kd[r] - gm) + EPS_) * mk;
        KP[e] = v;
        acc += v;
    }
    kpart[((size_t)bn * 32 + chunk) * M_ + m] = acc;
}

__global__ __launch_bounds__(256) void ksum_final_kernel(
    const float* __restrict__ part, float* __restrict__ ksum)
{
    int bn = blockIdx.x, m = threadIdx.x;
    float s = 0.f;
    #pragma unroll
    for (int c = 0; c < 32; c++) s += part[((size_t)bn * 32 + c) * M_ + m];
    ksum[(size_t)bn * M_ + m] = s;
}

// q' = ratio*(exp(qp-qd-rowmax)+eps) -> bf16; den = sum_m q'*ksum. rowmax from rmaxp partials.
__global__ __launch_bounds__(256) void qprime_den_kernel(
    const float* __restrict__ QP, const float* __restrict__ qd,
    const float* __restrict__ ksum, const float* __restrict__ rmaxp,
    float* __restrict__ den, __hip_bfloat16* __restrict__ QPb)
{
    size_t r = blockIdx.x;
    int n = (int)(r % NH_);
    int b = (int)(r / ((size_t)S_ * NH_));
    int bn = b * NH_ + n;
    float mx = fmaxf(rmaxp[r], rmaxp[R_ + r]);
    float v = QP[r * M_ + threadIdx.x];
    float qp = RATIO_ * (expf(v - qd[r] - mx) + EPS_);
    __hip_bfloat16 qb = __float2bfloat16(qp);
    QPb[r * M_ + threadIdx.x] = qb;
    float qpr = __bfloat162float(qb);
    float d = blockReduceSum(qpr * ksum[(size_t)bn * M_ + threadIdx.x]);
    if (threadIdx.x == 0) den[r] = d;
}

extern "C" void kernel_launch(void* const* d_in, const int* in_sizes, int n_in,
                              void* d_out, int out_size, void* d_ws, size_t ws_size,
                              hipStream_t stream)
{
    const int* input_ids  = (const int*)d_in[0];
    const int* token_type = (const int*)d_in[1];
    const int* position   = (const int*)d_in[2];
    const int* amask      = (const int*)d_in[3];
    const float* wemb = (const float*)d_in[4];
    const float* pemb = (const float*)d_in[5];
    const float* temb = (const float*)d_in[6];
    const float* elng = (const float*)d_in[7];
    const float* elnb = (const float*)d_in[8];
    const float* wq  = (const float*)d_in[9];
    const float* bq  = (const float*)d_in[10];
    const float* wk  = (const float*)d_in[11];
    const float* bk  = (const float*)d_in[12];
    const float* wv  = (const float*)d_in[13];
    const float* bv  = (const float*)d_in[14];
    const float* wo  = (const float*)d_in[15];
    const float* bo  = (const float*)d_in[16];
    const float* ln1g = (const float*)d_in[17];
    const float* ln1b = (const float*)d_in[18];
    const float* wi  = (const float*)d_in[19];
    const float* bi  = (const float*)d_in[20];
    const float* wo2 = (const float*)d_in[21];
    const float* bo2 = (const float*)d_in[22];
    const float* ln2g = (const float*)d_in[23];
    const float* ln2b = (const float*)d_in[24];
    const float* proj = (const float*)d_in[25];

    float* ws = (float*)d_ws;
    float* X    = ws;                          // 3145728
    float* T2   = X + 3145728;                 // 3145728
    float* BIG  = T2 + 3145728;                // 12582912
    float* U    = BIG + 12582912;              // 6291456 (PART fp32 3.1M f / QPb bf16 12.58M el)
    __hip_bfloat16* Xb  = (__hip_bfloat16*)(U + 6291456);            // 3145728 el
    __hip_bfloat16* Qb  = (__hip_bfloat16*)((float*)Xb + 1572864);   // Qb|Kb|Vb contiguous
    __hip_bfloat16* Kb  = Qb + 3145728;
    __hip_bfloat16* Vb  = Kb + 3145728;
    __hip_bfloat16* BF1 = Vb + 3145728;                              // 3145728 el
    __hip_bfloat16* WT  = BF1 + 3145728;                             // 7094272 el
    float* kvT_f = (float*)(WT + 7094272);     // kvT bf16 393216 el = 196608 f
    __hip_bfloat16* kvT = (__hip_bfloat16*)kvT_f;
    float* KSUM  = kvT_f + 196608;             // 6144
    float* KPART = KSUM + 6144;                // 196608 (24*32*256)
    float* RMAXP = KPART + 196608;             // 98304 ([2][R_])
    float* GMAX  = RMAXP + 98304;              // 64
    float* QD    = GMAX + 64;                  // 49152  (KD must follow)
    float* KD    = QD + 49152;                 // 49152
    float* DEN   = KD + 49152;                 // 49152
    float* BIASQ = DEN + 49152;                // 2304
    float* T1    = (float*)d_out;              // [4096,768] scratch aliasing output

    __hip_bfloat16* wqT  = WT;                 // packed QKV^T contiguous [2304,768]
    __hip_bfloat16* wkT  = wqT + 589824;
    __hip_bfloat16* wvT  = wkT + 589824;
    __hip_bfloat16* woT  = wvT + 589824;
    __hip_bfloat16* wiT  = woT + 589824;
    __hip_bfloat16* wo2T = wiT + 2359296;
    __hip_bfloat16* projb = wo2T + 2359296;    // 16384 el
    __hip_bfloat16* QPb = (__hip_bfloat16*)U;
    float* PART = U;
    __hip_bfloat16* BIGb = (__hip_bfloat16*)BIG;

    embed_ln_kernel<<<BS_, 256, 0, stream>>>(input_ids, token_type, position,
        wemb, pemb, temb, elng, elnb, X, Xb);

    const float sqscale = 0.5f * DN_ * DN_;
    for (int l = 0; l < L_; l++) {
        const float* wq_l = wq + (size_t)l * H_ * NH_ * HD_;
        const float* wk_l = wk + (size_t)l * H_ * NH_ * HD_;
        const float* wv_l = wv + (size_t)l * H_ * NH_ * HD_;
        const float* wo_l = wo + (size_t)l * NH_ * HD_ * H_;
        const float* bq_l = bq + (size_t)l * NH_ * HD_;
        const float* bk_l = bk + (size_t)l * NH_ * HD_;
        const float* bv_l = bv + (size_t)l * NH_ * HD_;
        const float* bo_l = bo + (size_t)l * H_;
        const float* wi_l = wi + (size_t)l * H_ * I_;
        const float* bi_l = bi + (size_t)l * I_;
        const float* wo2_l = wo2 + (size_t)l * I_ * H_;
        const float* bo2_l = bo2 + (size_t)l * H_;
        const float* proj_l = proj + (size_t)l * M_ * HD_;

        // ---- fused weight prep (1 launch) ----
        prep_kernel<<<6985, 256, 0, stream>>>(wq_l, wk_l, wv_l, wo_l, wi_l, wo2_l, proj_l,
            bq_l, bk_l, bv_l, wqT, wkT, wvT, woT, wiT, wo2T, projb, BIASQ);

        // ---- fused QKV GEMM -> Qb|Kb|Vb bf16 ----
        gemm_mfma_kernel<0,2,0><<<dim3(18,32), 256, 0, stream>>>(
            Xb, wqT, BIASQ, (void*)Qb, 2304, 768, 768, 768, 768, 1.f, nullptr);

        // ---- qd & kd in one pass (Qb,Kb contiguous; QD,KD contiguous) ----
        rowsq_bf16_kernel<<<2*R_/4, 256, 0, stream>>>(Qb, QD, sqscale);

        // ---- K path ----
        gemm_mfma_kernel<0,0,1><<<dim3(2,384), 256, 0, stream>>>(
            Kb, projb, nullptr, BIG, 256, 64, 64, 64, 256, DN_, RMAXP);
        gmax_kernel<<<B_*NH_, 256, 0, stream>>>(RMAXP, GMAX);
        kprime_ksum_kernel<<<dim3(B_*NH_, 32), 256, 0, stream>>>(BIG, KD, GMAX, amask, KPART);
        ksum_final_kernel<<<B_*NH_, 256, 0, stream>>>(KPART, KSUM);
        kv_splitk_kernel<<<dim3(4, B_*NH_, 8), 256, 0, stream>>>(BIG, Vb, PART);
        kvred_kernel<<<B_*NH_, 256, 0, stream>>>(PART, kvT);

        // ---- Q path ----
        gemm_mfma_kernel<0,0,1><<<dim3(2,384), 256, 0, stream>>>(
            Qb, projb, nullptr, BIG, 256, 64, 64, 64, 256, DN_, RMAXP);
        qprime_den_kernel<<<R_, 256, 0, stream>>>(BIG, QD, KSUM, RMAXP, DEN, QPb);
        num_mfma_kernel<<<dim3(16, B_*NH_), 256, 0, stream>>>(QPb, kvT, DEN, BF1);

        // ---- attn out proj + LN1 ----
        gemm_mfma_n64_kernel<<<dim3(12,32), 256, 0, stream>>>(
            BF1, woT, bo_l, T1, 768, 768, 768, 768);
        add_ln_kernel<<<BS_, 256, 0, stream>>>(T1, X, ln1g + (size_t)l*H_, ln1b + (size_t)l*H_, T2, BF1);

        // ---- FFN + LN2 ----
        gemm_mfma_kernel<1,1,0><<<dim3(24,32), 256, 0, stream>>>(
            BF1, wiT, bi_l, (void*)BIGb, 3072, 768, 768, 768, 3072, 1.f, nullptr);
        gemm_mfma_n64_kernel<<<dim3(12,32), 256, 0, stream>>>(
            BIGb, wo2T, bo2_l, T1, 3072, 3072, 3072, 768);
        float* xout = (l == L_ - 1) ? (float*)d_out : X;
        add_ln_kernel<<<BS_, 256, 0, stream>>>(T1, T2, ln2g + (size_t)l*H_, ln2b + (size_t)l*H_, xout, Xb);
    }
}